// Round 1
// baseline (269.508 us; speedup 1.0000x reference)
//
#include <hip/hip_runtime.h>
#include <hip/hip_bf16.h>
#include <stdint.h>

using u16 = unsigned short;

typedef __attribute__((ext_vector_type(8))) short bf16x8;
typedef __attribute__((ext_vector_type(4))) float f32x4;

__device__ inline u16 f2b(float x) {
  union { float f; uint32_t u; } v; v.f = x;
  uint32_t r = (v.u + 0x7FFFu + ((v.u >> 16) & 1u)) >> 16;
  return (u16)r;
}
__device__ inline float b2f(u16 b) {
  union { uint32_t u; float f; } v; v.u = ((uint32_t)b) << 16;
  return v.f;
}

__device__ inline void store_out(float* p, float v) { *p = v; }
__device__ inline void store_out(u16* p, float v) { *p = f2b(v); }

// ---------------------------------------------------------------------------
// C[M x N] = A[M x K](bf16) * Bt[N x K](bf16)^T + bias[M]
// 128x128 block tile, BK=32, 4 waves (2x2), each wave 4x4 of 16x16x32 MFMA.
// M, N multiples of 128; K multiple of 32.
// ---------------------------------------------------------------------------
template<typename OutT>
__global__ __launch_bounds__(256)
void gemm_bt(const u16* __restrict__ A, const u16* __restrict__ Bt,
             const float* __restrict__ bias, OutT* __restrict__ C,
             int M, int N, int K)
{
  __shared__ u16 As[128 * 32];
  __shared__ u16 Bs[128 * 32];

  const int tid  = threadIdx.x;
  const int wave = tid >> 6;
  const int lane = tid & 63;
  const int wm = wave >> 1, wn = wave & 1;
  const int lr = lane & 15;   // A: m-in-16 / B: n-in-16 / D: col
  const int lq = lane >> 4;   // quad

  const int m0 = blockIdx.y * 128;
  const int n0 = blockIdx.x * 128;

  const u16* gA = A  + (size_t)m0 * K;
  const u16* gB = Bt + (size_t)n0 * K;

  f32x4 acc[4][4];
  #pragma unroll
  for (int i = 0; i < 4; ++i)
    #pragma unroll
    for (int j = 0; j < 4; ++j)
      acc[i][j] = (f32x4){0.f, 0.f, 0.f, 0.f};

  const int srow = tid >> 2;          // 0..63 staging row (first half)
  const int skc  = (tid & 3) << 3;    // k offset in bf16 elems (0,8,16,24)

  for (int k0 = 0; k0 < K; k0 += 32) {
    #pragma unroll
    for (int i = 0; i < 2; ++i) {
      const int row = srow + i * 64;
      const uint4 va = *(const uint4*)(gA + (size_t)row * K + k0 + skc);
      const uint4 vb = *(const uint4*)(gB + (size_t)row * K + k0 + skc);
      *(uint4*)&As[row * 32 + skc] = va;
      *(uint4*)&Bs[row * 32 + skc] = vb;
    }
    __syncthreads();

    bf16x8 af[4], bfr[4];
    #pragma unroll
    for (int im = 0; im < 4; ++im)
      af[im] = *(const bf16x8*)&As[(wm * 64 + im * 16 + lr) * 32 + lq * 8];
    #pragma unroll
    for (int in = 0; in < 4; ++in)
      bfr[in] = *(const bf16x8*)&Bs[(wn * 64 + in * 16 + lr) * 32 + lq * 8];

    #pragma unroll
    for (int im = 0; im < 4; ++im)
      #pragma unroll
      for (int in = 0; in < 4; ++in)
        acc[im][in] = __builtin_amdgcn_mfma_f32_16x16x32_bf16(
            af[im], bfr[in], acc[im][in], 0, 0, 0);

    __syncthreads();
  }

  // epilogue: D element (row = lq*4+r, col = lr) within each 16x16 tile
  #pragma unroll
  for (int im = 0; im < 4; ++im) {
    const int mbase = m0 + wm * 64 + im * 16 + lq * 4;
    #pragma unroll
    for (int in = 0; in < 4; ++in) {
      const int ncol = n0 + wn * 64 + in * 16 + lr;
      #pragma unroll
      for (int r = 0; r < 4; ++r) {
        const int m = mbase + r;
        store_out(C + (size_t)m * N + ncol, acc[im][in][r] + bias[m]);
      }
    }
  }
}

// fp32 [R x C] -> bf16 [C x R]
__global__ __launch_bounds__(256)
void cast_transpose(const float* __restrict__ in, u16* __restrict__ out,
                    int R, int C)
{
  __shared__ u16 tile[32][33];
  const int c0 = blockIdx.x * 32, r0 = blockIdx.y * 32;
  const int tx = threadIdx.x & 31, ty = threadIdx.x >> 5;
  #pragma unroll
  for (int k = 0; k < 4; ++k)
    tile[ty + 8 * k][tx] = f2b(in[(size_t)(r0 + ty + 8 * k) * C + c0 + tx]);
  __syncthreads();
  #pragma unroll
  for (int k = 0; k < 4; ++k)
    out[(size_t)(c0 + ty + 8 * k) * R + r0 + tx] = tile[tx][ty + 8 * k];
}

// bf16 [R x C] -> bf16 [C x R]
__global__ __launch_bounds__(256)
void transpose_u16(const u16* __restrict__ in, u16* __restrict__ out,
                   int R, int C)
{
  __shared__ u16 tile[32][33];
  const int c0 = blockIdx.x * 32, r0 = blockIdx.y * 32;
  const int tx = threadIdx.x & 31, ty = threadIdx.x >> 5;
  #pragma unroll
  for (int k = 0; k < 4; ++k)
    tile[ty + 8 * k][tx] = in[(size_t)(r0 + ty + 8 * k) * C + c0 + tx];
  __syncthreads();
  #pragma unroll
  for (int k = 0; k < 4; ++k)
    out[(size_t)(c0 + ty + 8 * k) * R + r0 + tx] = tile[tx][ty + 8 * k];
}

__global__ __launch_bounds__(256)
void cast_f32_bf16(const float4* __restrict__ in, ushort4* __restrict__ out,
                   int n4)
{
  const int i = blockIdx.x * 256 + threadIdx.x;
  if (i >= n4) return;
  const float4 v = in[i];
  ushort4 o;
  o.x = f2b(v.x); o.y = f2b(v.y); o.z = f2b(v.z); o.w = f2b(v.w);
  out[i] = o;
}

// score[h][n] += (1/32) * sum_{c in chunk} Q[c][n] * keys[h*1024+c][n]
__global__ __launch_bounds__(256)
void score_partial(const u16* __restrict__ keys, const float* __restrict__ Q,
                   float* __restrict__ score)
{
  const int n  = blockIdx.x * 256 + threadIdx.x;
  const int c0 = blockIdx.y * 128;
  float s[4] = {0.f, 0.f, 0.f, 0.f};
  for (int c = c0; c < c0 + 128; ++c) {
    const float q = Q[(size_t)c * 4096 + n];
    #pragma unroll
    for (int h = 0; h < 4; ++h)
      s[h] = fmaf(q, b2f(keys[((size_t)((h << 10) + c)) * 4096 + n]), s[h]);
  }
  #pragma unroll
  for (int h = 0; h < 4; ++h)
    atomicAdd(&score[h * 4096 + n], s[h] * 0.03125f);
}

// softmax over 4 heads -> weightmap (also serves as weight input to z_ln)
__global__ __launch_bounds__(256)
void softmax_h(const float* __restrict__ score, float* __restrict__ wmap)
{
  const int n = blockIdx.x * 256 + threadIdx.x;
  const float s0 = score[n], s1 = score[4096 + n];
  const float s2 = score[8192 + n], s3 = score[12288 + n];
  const float m = fmaxf(fmaxf(s0, s1), fmaxf(s2, s3));
  const float e0 = expf(s0 - m), e1 = expf(s1 - m);
  const float e2 = expf(s2 - m), e3 = expf(s3 - m);
  const float inv = 1.f / (e0 + e1 + e2 + e3);
  wmap[n] = e0 * inv; wmap[4096 + n] = e1 * inv;
  wmap[8192 + n] = e2 * inv; wmap[12288 + n] = e3 * inv;
}

// z = sum_h w[h][n]*keys[h][c][n]; t = z + Q; LayerNorm over n; bf16 out
__global__ __launch_bounds__(256)
void z_ln(const u16* __restrict__ keys, const float* __restrict__ Q,
          const float* __restrict__ w, const float* __restrict__ g,
          const float* __restrict__ bb, u16* __restrict__ fused)
{
  const int c  = blockIdx.x;
  const int tx = threadIdx.x;
  float t[16];
  float s = 0.f, s2 = 0.f;
  #pragma unroll
  for (int j = 0; j < 16; ++j) {
    const int n = tx + j * 256;
    const float q = Q[(size_t)c * 4096 + n];
    float z = 0.f;
    #pragma unroll
    for (int h = 0; h < 4; ++h)
      z = fmaf(w[h * 4096 + n], b2f(keys[((size_t)((h << 10) + c)) * 4096 + n]), z);
    const float v = z + q;
    t[j] = v; s += v; s2 = fmaf(v, v, s2);
  }
  #pragma unroll
  for (int o = 32; o > 0; o >>= 1) {
    s  += __shfl_down(s, o);
    s2 += __shfl_down(s2, o);
  }
  __shared__ float rbuf[8];
  const int wave = tx >> 6, lane = tx & 63;
  if (lane == 0) { rbuf[wave] = s; rbuf[4 + wave] = s2; }
  __syncthreads();
  s  = rbuf[0] + rbuf[1] + rbuf[2] + rbuf[3];
  s2 = rbuf[4] + rbuf[5] + rbuf[6] + rbuf[7];
  const float mu  = s * (1.f / 4096.f);
  const float var = s2 * (1.f / 4096.f) - mu * mu;
  const float rs  = rsqrtf(var + 1e-5f);
  #pragma unroll
  for (int j = 0; j < 16; ++j) {
    const int n = tx + j * 256;
    fused[(size_t)c * 4096 + n] = f2b((t[j] - mu) * rs * g[n] + bb[n]);
  }
}

extern "C" void kernel_launch(void* const* d_in, const int* in_sizes, int n_in,
                              void* d_out, int out_size, void* d_ws, size_t ws_size,
                              hipStream_t stream)
{
  const float* P   = (const float*)d_in[0];  // [1,1024,4096]
  const float* I   = (const float*)d_in[1];  // [1,1024,4096]
  const float* Wim = (const float*)d_in[2];  // [4,1024,1024]
  const float* bim = (const float*)d_in[3];  // [4,1024]
  const float* WL  = (const float*)d_in[4];  // [1024,1024]
  const float* bL  = (const float*)d_in[5];  // [1024]
  const float* lng = (const float*)d_in[6];  // [4096]
  const float* lnb = (const float*)d_in[7];  // [4096]
  const float* Wf  = (const float*)d_in[8];  // [1024,1024]
  const float* bf_ = (const float*)d_in[9];  // [1024]
  float* out = (float*)d_out;                // [1024*4096] fusion + [4*4096] wmap

  char* ws = (char*)d_ws;
  u16*   PT     = (u16*)(ws + 0);                    //  8 MB  [4096 x 1024] bf16
  u16*   IT     = (u16*)(ws + (size_t)8  * 1048576); //  8 MB
  u16*   WLb    = (u16*)(ws + (size_t)16 * 1048576); //  2 MB
  u16*   WIb    = (u16*)(ws + (size_t)18 * 1048576); //  8 MB
  u16*   WFb    = (u16*)(ws + (size_t)26 * 1048576); //  2 MB
  float* Q      = (float*)(ws + (size_t)28 * 1048576); // 16 MB [1024 x 4096]
  u16*   KEYS   = (u16*)(ws + (size_t)44 * 1048576); // 32 MB [4096 x 4096] bf16
  float* SCORE  = (float*)(ws + (size_t)76 * 1048576); // 64 KB [4 x 4096]
  u16*   FUSED  = (u16*)(ws + (size_t)77 * 1048576); //  8 MB [1024 x 4096] bf16
  u16*   FUSEDT = (u16*)(ws + (size_t)85 * 1048576); //  8 MB [4096 x 1024] bf16

  const dim3 b256(256);

  // bf16 casts / transposes
  cast_transpose<<<dim3(128, 32), b256, 0, stream>>>(P, PT, 1024, 4096);
  cast_transpose<<<dim3(128, 32), b256, 0, stream>>>(I, IT, 1024, 4096);
  cast_f32_bf16<<<1024, b256, 0, stream>>>((const float4*)WL,  (ushort4*)WLb, 262144);
  cast_f32_bf16<<<4096, b256, 0, stream>>>((const float4*)Wim, (ushort4*)WIb, 1048576);
  cast_f32_bf16<<<1024, b256, 0, stream>>>((const float4*)Wf,  (ushort4*)WFb, 262144);

  // Q = W_L * P + b_L   [1024 x 4096] fp32
  gemm_bt<float><<<dim3(32, 8), b256, 0, stream>>>(WLb, PT, bL, Q, 1024, 4096, 1024);
  // keys = W_img * I + b_img  [4096 x 4096] bf16 (4 heads stacked on M)
  gemm_bt<u16><<<dim3(32, 32), b256, 0, stream>>>(WIb, IT, bim, KEYS, 4096, 4096, 1024);

  // score + softmax -> weightmap (written straight into d_out tail)
  hipMemsetAsync(SCORE, 0, 4 * 4096 * sizeof(float), stream);
  score_partial<<<dim3(16, 8), b256, 0, stream>>>(KEYS, Q, SCORE);
  float* wmap = out + (size_t)1024 * 4096;
  softmax_h<<<16, b256, 0, stream>>>(SCORE, wmap);

  // z + residual + LayerNorm -> bf16, then transpose for final GEMM
  z_ln<<<1024, b256, 0, stream>>>(KEYS, Q, wmap, lng, lnb, FUSED);
  transpose_u16<<<dim3(128, 32), b256, 0, stream>>>(FUSED, FUSEDT, 1024, 4096);

  // out = W_f * fused + b_f  [1024 x 4096] fp32 -> d_out head
  gemm_bt<float><<<dim3(32, 8), b256, 0, stream>>>(WFb, FUSEDT, bf_, out, 1024, 4096, 1024);
}

// Round 2
// 254.861 us; speedup vs baseline: 1.0575x; 1.0575x over previous
//
#include <hip/hip_runtime.h>
#include <hip/hip_bf16.h>
#include <stdint.h>

using u16 = unsigned short;

typedef __attribute__((ext_vector_type(8))) short bf16x8;
typedef __attribute__((ext_vector_type(4))) float f32x4;

typedef const __attribute__((address_space(1))) unsigned int* gas_t;
typedef __attribute__((address_space(3))) unsigned int* las_t;

__device__ inline void g2l16(const u16* g, u16* l) {
  // async global->LDS, 16 B per lane; LDS dest = wave-uniform base + lane*16
  __builtin_amdgcn_global_load_lds((gas_t)g, (las_t)l, 16, 0, 0);
}

__device__ inline u16 f2b(float x) {
  union { float f; uint32_t u; } v; v.f = x;
  uint32_t r = (v.u + 0x7FFFu + ((v.u >> 16) & 1u)) >> 16;
  return (u16)r;
}
__device__ inline float b2f(u16 b) {
  union { uint32_t u; float f; } v; v.u = ((uint32_t)b) << 16;
  return v.f;
}

__device__ inline void store_out(float* p, float v) { *p = v; }
__device__ inline void store_out(u16* p, float v) { *p = f2b(v); }

// ---------------------------------------------------------------------------
// C[M x N] = A[M x K](bf16) * Bt[N x K](bf16)^T + bias[M]
// 128x128 tile, BK=32, 4 waves (2x2), 4x4 of 16x16x32 MFMA per wave.
// global_load_lds(16B) staging: thread tid's LDS slot is byte tid*16, which
// matches (row=tid>>2, kchunk=(tid&3)*8) in the [row][32] LDS layout.
// ---------------------------------------------------------------------------
template<typename OutT>
__global__ __launch_bounds__(256)
void gemm_bt(const u16* __restrict__ A, const u16* __restrict__ Bt,
             const float* __restrict__ bias, OutT* __restrict__ C,
             int M, int N, int K)
{
  __shared__ u16 As[128 * 32];
  __shared__ u16 Bs[128 * 32];

  const int tid  = threadIdx.x;
  const int wave = tid >> 6;
  const int lane = tid & 63;
  const int wm = wave >> 1, wn = wave & 1;
  const int lr = lane & 15;
  const int lq = lane >> 4;

  const int m0 = blockIdx.y * 128;
  const int n0 = blockIdx.x * 128;

  // per-lane global source for staging
  const u16* gA = A  + (size_t)(m0 + (tid >> 2)) * K + ((tid & 3) << 3);
  const u16* gB = Bt + (size_t)(n0 + (tid >> 2)) * K + ((tid & 3) << 3);
  // wave-uniform LDS staging bases (bytes: wave*1024)
  u16* dstA = As + wave * 512;
  u16* dstB = Bs + wave * 512;

  f32x4 acc[4][4];
  #pragma unroll
  for (int i = 0; i < 4; ++i)
    #pragma unroll
    for (int j = 0; j < 4; ++j)
      acc[i][j] = (f32x4){0.f, 0.f, 0.f, 0.f};

  for (int k0 = 0; k0 < K; k0 += 32) {
    g2l16(gA + k0,                dstA);          // A rows   0..63
    g2l16(gA + (size_t)64 * K + k0, dstA + 2048); // A rows  64..127
    g2l16(gB + k0,                dstB);          // B rows   0..63
    g2l16(gB + (size_t)64 * K + k0, dstB + 2048); // B rows  64..127
    __syncthreads();

    bf16x8 af[4], bfr[4];
    #pragma unroll
    for (int im = 0; im < 4; ++im)
      af[im] = *(const bf16x8*)&As[(wm * 64 + im * 16 + lr) * 32 + lq * 8];
    #pragma unroll
    for (int in = 0; in < 4; ++in)
      bfr[in] = *(const bf16x8*)&Bs[(wn * 64 + in * 16 + lr) * 32 + lq * 8];

    #pragma unroll
    for (int im = 0; im < 4; ++im)
      #pragma unroll
      for (int in = 0; in < 4; ++in)
        acc[im][in] = __builtin_amdgcn_mfma_f32_16x16x32_bf16(
            af[im], bfr[in], acc[im][in], 0, 0, 0);

    __syncthreads();
  }

  #pragma unroll
  for (int im = 0; im < 4; ++im) {
    const int mbase = m0 + wm * 64 + im * 16 + lq * 4;
    #pragma unroll
    for (int in = 0; in < 4; ++in) {
      const int ncol = n0 + wn * 64 + in * 16 + lr;
      #pragma unroll
      for (int r = 0; r < 4; ++r) {
        const int m = mbase + r;
        store_out(C + (size_t)m * N + ncol, acc[im][in][r] + bias[m]);
      }
    }
  }
}

// ---------------------------------------------------------------------------
// 64x128 tile variant for M=1024 GEMMs: 512 blocks -> 2 blocks/CU.
// 4 waves side-by-side in N; each wave: 64x32 = 4x2 of 16x16 tiles.
// ---------------------------------------------------------------------------
template<typename OutT>
__global__ __launch_bounds__(256)
void gemm_bt_64(const u16* __restrict__ A, const u16* __restrict__ Bt,
                const float* __restrict__ bias, OutT* __restrict__ C,
                int M, int N, int K)
{
  __shared__ u16 As[64 * 32];    // 4 KB
  __shared__ u16 Bs[128 * 32];   // 8 KB

  const int tid  = threadIdx.x;
  const int wave = tid >> 6;
  const int lane = tid & 63;
  const int lr = lane & 15;
  const int lq = lane >> 4;

  const int m0 = blockIdx.y * 64;
  const int n0 = blockIdx.x * 128;

  const u16* gA = A  + (size_t)(m0 + (tid >> 2)) * K + ((tid & 3) << 3);
  const u16* gB = Bt + (size_t)(n0 + (tid >> 2)) * K + ((tid & 3) << 3);
  u16* dstA = As + wave * 512;
  u16* dstB = Bs + wave * 512;

  f32x4 acc[4][2];
  #pragma unroll
  for (int i = 0; i < 4; ++i)
    #pragma unroll
    for (int j = 0; j < 2; ++j)
      acc[i][j] = (f32x4){0.f, 0.f, 0.f, 0.f};

  for (int k0 = 0; k0 < K; k0 += 32) {
    g2l16(gA + k0,                  dstA);          // A rows 0..63
    g2l16(gB + k0,                  dstB);          // B rows 0..63
    g2l16(gB + (size_t)64 * K + k0, dstB + 2048);   // B rows 64..127
    __syncthreads();

    bf16x8 af[4], bfr[2];
    #pragma unroll
    for (int im = 0; im < 4; ++im)
      af[im] = *(const bf16x8*)&As[(im * 16 + lr) * 32 + lq * 8];
    #pragma unroll
    for (int in = 0; in < 2; ++in)
      bfr[in] = *(const bf16x8*)&Bs[(wave * 32 + in * 16 + lr) * 32 + lq * 8];

    #pragma unroll
    for (int im = 0; im < 4; ++im)
      #pragma unroll
      for (int in = 0; in < 2; ++in)
        acc[im][in] = __builtin_amdgcn_mfma_f32_16x16x32_bf16(
            af[im], bfr[in], acc[im][in], 0, 0, 0);

    __syncthreads();
  }

  #pragma unroll
  for (int im = 0; im < 4; ++im) {
    const int mbase = m0 + im * 16 + lq * 4;
    #pragma unroll
    for (int in = 0; in < 2; ++in) {
      const int ncol = n0 + wave * 32 + in * 16 + lr;
      #pragma unroll
      for (int r = 0; r < 4; ++r) {
        const int m = mbase + r;
        store_out(C + (size_t)m * N + ncol, acc[im][in][r] + bias[m]);
      }
    }
  }
}

// fp32 [R x C] -> bf16 [C x R]
__global__ __launch_bounds__(256)
void cast_transpose(const float* __restrict__ in, u16* __restrict__ out,
                    int R, int C)
{
  __shared__ u16 tile[32][33];
  const int c0 = blockIdx.x * 32, r0 = blockIdx.y * 32;
  const int tx = threadIdx.x & 31, ty = threadIdx.x >> 5;
  #pragma unroll
  for (int k = 0; k < 4; ++k)
    tile[ty + 8 * k][tx] = f2b(in[(size_t)(r0 + ty + 8 * k) * C + c0 + tx]);
  __syncthreads();
  #pragma unroll
  for (int k = 0; k < 4; ++k)
    out[(size_t)(c0 + ty + 8 * k) * R + r0 + tx] = tile[tx][ty + 8 * k];
}

// bf16 [R x C] -> bf16 [C x R]
__global__ __launch_bounds__(256)
void transpose_u16(const u16* __restrict__ in, u16* __restrict__ out,
                   int R, int C)
{
  __shared__ u16 tile[32][33];
  const int c0 = blockIdx.x * 32, r0 = blockIdx.y * 32;
  const int tx = threadIdx.x & 31, ty = threadIdx.x >> 5;
  #pragma unroll
  for (int k = 0; k < 4; ++k)
    tile[ty + 8 * k][tx] = in[(size_t)(r0 + ty + 8 * k) * C + c0 + tx];
  __syncthreads();
  #pragma unroll
  for (int k = 0; k < 4; ++k)
    out[(size_t)(c0 + ty + 8 * k) * R + r0 + tx] = tile[tx][ty + 8 * k];
}

__global__ __launch_bounds__(256)
void cast_f32_bf16(const float4* __restrict__ in, ushort4* __restrict__ out,
                   int n4)
{
  const int i = blockIdx.x * 256 + threadIdx.x;
  if (i >= n4) return;
  const float4 v = in[i];
  ushort4 o;
  o.x = f2b(v.x); o.y = f2b(v.y); o.z = f2b(v.z); o.w = f2b(v.w);
  out[i] = o;
}

// score[h][n] += (1/32) * sum_{c in chunk} Q[c][n] * keys[h*1024+c][n]
__global__ __launch_bounds__(256)
void score_partial(const u16* __restrict__ keys, const float* __restrict__ Q,
                   float* __restrict__ score)
{
  const int n  = blockIdx.x * 256 + threadIdx.x;
  const int c0 = blockIdx.y * 128;
  float s[4] = {0.f, 0.f, 0.f, 0.f};
  for (int c = c0; c < c0 + 128; ++c) {
    const float q = Q[(size_t)c * 4096 + n];
    #pragma unroll
    for (int h = 0; h < 4; ++h)
      s[h] = fmaf(q, b2f(keys[((size_t)((h << 10) + c)) * 4096 + n]), s[h]);
  }
  #pragma unroll
  for (int h = 0; h < 4; ++h)
    atomicAdd(&score[h * 4096 + n], s[h] * 0.03125f);
}

// softmax over 4 heads -> weightmap
__global__ __launch_bounds__(256)
void softmax_h(const float* __restrict__ score, float* __restrict__ wmap)
{
  const int n = blockIdx.x * 256 + threadIdx.x;
  const float s0 = score[n], s1 = score[4096 + n];
  const float s2 = score[8192 + n], s3 = score[12288 + n];
  const float m = fmaxf(fmaxf(s0, s1), fmaxf(s2, s3));
  const float e0 = expf(s0 - m), e1 = expf(s1 - m);
  const float e2 = expf(s2 - m), e3 = expf(s3 - m);
  const float inv = 1.f / (e0 + e1 + e2 + e3);
  wmap[n] = e0 * inv; wmap[4096 + n] = e1 * inv;
  wmap[8192 + n] = e2 * inv; wmap[12288 + n] = e3 * inv;
}

// z = sum_h w[h][n]*keys[h][c][n]; t = z + Q; LayerNorm over n; bf16 out
__global__ __launch_bounds__(256)
void z_ln(const u16* __restrict__ keys, const float* __restrict__ Q,
          const float* __restrict__ w, const float* __restrict__ g,
          const float* __restrict__ bb, u16* __restrict__ fused)
{
  const int c  = blockIdx.x;
  const int tx = threadIdx.x;
  float t[16];
  float s = 0.f, s2 = 0.f;
  #pragma unroll
  for (int j = 0; j < 16; ++j) {
    const int n = tx + j * 256;
    const float q = Q[(size_t)c * 4096 + n];
    float z = 0.f;
    #pragma unroll
    for (int h = 0; h < 4; ++h)
      z = fmaf(w[h * 4096 + n], b2f(keys[((size_t)((h << 10) + c)) * 4096 + n]), z);
    const float v = z + q;
    t[j] = v; s += v; s2 = fmaf(v, v, s2);
  }
  #pragma unroll
  for (int o = 32; o > 0; o >>= 1) {
    s  += __shfl_down(s, o);
    s2 += __shfl_down(s2, o);
  }
  __shared__ float rbuf[8];
  const int wave = tx >> 6, lane = tx & 63;
  if (lane == 0) { rbuf[wave] = s; rbuf[4 + wave] = s2; }
  __syncthreads();
  s  = rbuf[0] + rbuf[1] + rbuf[2] + rbuf[3];
  s2 = rbuf[4] + rbuf[5] + rbuf[6] + rbuf[7];
  const float mu  = s * (1.f / 4096.f);
  const float var = s2 * (1.f / 4096.f) - mu * mu;
  const float rs  = rsqrtf(var + 1e-5f);
  #pragma unroll
  for (int j = 0; j < 16; ++j) {
    const int n = tx + j * 256;
    fused[(size_t)c * 4096 + n] = f2b((t[j] - mu) * rs * g[n] + bb[n]);
  }
}

extern "C" void kernel_launch(void* const* d_in, const int* in_sizes, int n_in,
                              void* d_out, int out_size, void* d_ws, size_t ws_size,
                              hipStream_t stream)
{
  const float* P   = (const float*)d_in[0];  // [1,1024,4096]
  const float* I   = (const float*)d_in[1];  // [1,1024,4096]
  const float* Wim = (const float*)d_in[2];  // [4,1024,1024]
  const float* bim = (const float*)d_in[3];  // [4,1024]
  const float* WL  = (const float*)d_in[4];  // [1024,1024]
  const float* bL  = (const float*)d_in[5];  // [1024]
  const float* lng = (const float*)d_in[6];  // [4096]
  const float* lnb = (const float*)d_in[7];  // [4096]
  const float* Wf  = (const float*)d_in[8];  // [1024,1024]
  const float* bf_ = (const float*)d_in[9];  // [1024]
  float* out = (float*)d_out;                // [1024*4096] fusion + [4*4096] wmap

  char* ws = (char*)d_ws;
  u16*   PT     = (u16*)(ws + 0);                    //  8 MB  [4096 x 1024] bf16
  u16*   IT     = (u16*)(ws + (size_t)8  * 1048576); //  8 MB
  u16*   WLb    = (u16*)(ws + (size_t)16 * 1048576); //  2 MB
  u16*   WIb    = (u16*)(ws + (size_t)18 * 1048576); //  8 MB
  u16*   WFb    = (u16*)(ws + (size_t)26 * 1048576); //  2 MB
  float* Q      = (float*)(ws + (size_t)28 * 1048576); // 16 MB [1024 x 4096]
  u16*   KEYS   = (u16*)(ws + (size_t)44 * 1048576); // 32 MB [4096 x 4096] bf16
  float* SCORE  = (float*)(ws + (size_t)76 * 1048576); // 64 KB [4 x 4096]
  u16*   FUSED  = (u16*)(ws + (size_t)77 * 1048576); //  8 MB [1024 x 4096] bf16
  u16*   FUSEDT = (u16*)(ws + (size_t)85 * 1048576); //  8 MB [4096 x 1024] bf16

  const dim3 b256(256);

  // bf16 casts / transposes
  cast_transpose<<<dim3(128, 32), b256, 0, stream>>>(P, PT, 1024, 4096);
  cast_transpose<<<dim3(128, 32), b256, 0, stream>>>(I, IT, 1024, 4096);
  cast_f32_bf16<<<1024, b256, 0, stream>>>((const float4*)WL,  (ushort4*)WLb, 262144);
  cast_f32_bf16<<<4096, b256, 0, stream>>>((const float4*)Wim, (ushort4*)WIb, 1048576);
  cast_f32_bf16<<<1024, b256, 0, stream>>>((const float4*)Wf,  (ushort4*)WFb, 262144);

  // Q = W_L * P + b_L   [1024 x 4096] fp32  (64x128 tiles -> 512 blocks)
  gemm_bt_64<float><<<dim3(32, 16), b256, 0, stream>>>(WLb, PT, bL, Q, 1024, 4096, 1024);
  // keys = W_img * I + b_img  [4096 x 4096] bf16 (128x128 tiles -> 1024 blocks)
  gemm_bt<u16><<<dim3(32, 32), b256, 0, stream>>>(WIb, IT, bim, KEYS, 4096, 4096, 1024);

  // score + softmax -> weightmap (written straight into d_out tail)
  hipMemsetAsync(SCORE, 0, 4 * 4096 * sizeof(float), stream);
  score_partial<<<dim3(16, 8), b256, 0, stream>>>(KEYS, Q, SCORE);
  float* wmap = out + (size_t)1024 * 4096;
  softmax_h<<<16, b256, 0, stream>>>(SCORE, wmap);

  // z + residual + LayerNorm -> bf16, then transpose for final GEMM
  z_ln<<<1024, b256, 0, stream>>>(KEYS, Q, wmap, lng, lnb, FUSED);
  transpose_u16<<<dim3(128, 32), b256, 0, stream>>>(FUSED, FUSEDT, 1024, 4096);

  // out = W_f * fused + b_f  [1024 x 4096] fp32 -> d_out head
  gemm_bt_64<float><<<dim3(32, 16), b256, 0, stream>>>(WFb, FUSEDT, bf_, out, 1024, 4096, 1024);
}

// Round 3
// 232.018 us; speedup vs baseline: 1.1616x; 1.0985x over previous
//
#include <hip/hip_runtime.h>
#include <hip/hip_bf16.h>
#include <stdint.h>

using u16 = unsigned short;

typedef __attribute__((ext_vector_type(8))) short bf16x8;
typedef __attribute__((ext_vector_type(4))) float f32x4;

typedef const __attribute__((address_space(1))) unsigned int* gas_t;
typedef __attribute__((address_space(3))) unsigned int* las_t;

__device__ inline void g2l16(const u16* g, u16* l) {
  // async global->LDS, 16 B per lane; LDS dest = wave-uniform base + lane*16
  __builtin_amdgcn_global_load_lds((gas_t)g, (las_t)l, 16, 0, 0);
}

__device__ inline u16 f2b(float x) {
  union { float f; uint32_t u; } v; v.f = x;
  uint32_t r = (v.u + 0x7FFFu + ((v.u >> 16) & 1u)) >> 16;
  return (u16)r;
}
__device__ inline float b2f(u16 b) {
  union { uint32_t u; float f; } v; v.u = ((uint32_t)b) << 16;
  return v.f;
}

__device__ inline void store_out(float* p, float v) { *p = v; }
__device__ inline void store_out(u16* p, float v) { *p = f2b(v); }

// ---------------------------------------------------------------------------
// C[M x N] = A[M x K](bf16) * Bt[N x K](bf16)^T + bias[M]
// 128x128 tile, BK=64, 4 waves (2x2), 2 ksubs x 16 MFMA (16x16x32) per wave.
// LDS rows are 64 elems (128 B = all 32 banks). XOR swizzle: physical 16B
// chunk p holds logical chunk p ^ (row&7); applied on the global source of
// global_load_lds (dest is fixed lane-contiguous). Reads: consecutive 8
// lanes hit all 8 bank groups -> conflict-free.
// ---------------------------------------------------------------------------
template<typename OutT>
__global__ __launch_bounds__(256)
void gemm_bt(const u16* __restrict__ A, const u16* __restrict__ Bt,
             const float* __restrict__ bias, OutT* __restrict__ C,
             int M, int N, int K)
{
  __shared__ u16 As[128 * 64];   // 16 KB
  __shared__ u16 Bs[128 * 64];   // 16 KB

  const int tid  = threadIdx.x;
  const int wave = tid >> 6;
  const int lane = tid & 63;
  const int wm = wave >> 1, wn = wave & 1;
  const int lr = lane & 15;
  const int lq = lane >> 4;
  const int x7 = lr & 7;         // row&7 for all fragment rows

  const int m0 = blockIdx.y * 128;
  const int n0 = blockIdx.x * 128;

  // staging: 4 row-segments of 32 rows; thread -> (row=tid>>3, phys chunk=tid&7)
  const int srow = tid >> 3;            // 0..31
  const int sgc  = (tid & 7) ^ (srow & 7); // swizzled global chunk
  const u16* gA = A  + (size_t)(m0 + srow) * K + sgc * 8;
  const u16* gB = Bt + (size_t)(n0 + srow) * K + sgc * 8;
  u16* dstA = As + wave * 512;          // +s*2048 per segment (u16 units)
  u16* dstB = Bs + wave * 512;

  f32x4 acc[4][4];
  #pragma unroll
  for (int i = 0; i < 4; ++i)
    #pragma unroll
    for (int j = 0; j < 4; ++j)
      acc[i][j] = (f32x4){0.f, 0.f, 0.f, 0.f};

  for (int k0 = 0; k0 < K; k0 += 64) {
    #pragma unroll
    for (int s = 0; s < 4; ++s) {
      g2l16(gA + (size_t)(s * 32) * K + k0, dstA + s * 2048);
      g2l16(gB + (size_t)(s * 32) * K + k0, dstB + s * 2048);
    }
    __syncthreads();

    #pragma unroll
    for (int ks = 0; ks < 2; ++ks) {
      const int pa = (ks * 4 + lq) ^ x7;   // physical chunk for this ksub
      bf16x8 af[4], bfr[4];
      #pragma unroll
      for (int im = 0; im < 4; ++im)
        af[im] = *(const bf16x8*)&As[(wm * 64 + im * 16 + lr) * 64 + pa * 8];
      #pragma unroll
      for (int in = 0; in < 4; ++in)
        bfr[in] = *(const bf16x8*)&Bs[(wn * 64 + in * 16 + lr) * 64 + pa * 8];

      #pragma unroll
      for (int im = 0; im < 4; ++im)
        #pragma unroll
        for (int in = 0; in < 4; ++in)
          acc[im][in] = __builtin_amdgcn_mfma_f32_16x16x32_bf16(
              af[im], bfr[in], acc[im][in], 0, 0, 0);
    }
    __syncthreads();
  }

  #pragma unroll
  for (int im = 0; im < 4; ++im) {
    const int mbase = m0 + wm * 64 + im * 16 + lq * 4;
    #pragma unroll
    for (int in = 0; in < 4; ++in) {
      const int ncol = n0 + wn * 64 + in * 16 + lr;
      #pragma unroll
      for (int r = 0; r < 4; ++r) {
        const int m = mbase + r;
        store_out(C + (size_t)m * N + ncol, acc[im][in][r] + bias[m]);
      }
    }
  }
}

// ---------------------------------------------------------------------------
// 64x128 tile variant (M=1024 GEMMs -> 512 blocks, 2/CU). BK=64, swizzled.
// 4 waves side-by-side in N; each wave 64x32 = 4x2 of 16x16 tiles.
// ---------------------------------------------------------------------------
template<typename OutT>
__global__ __launch_bounds__(256)
void gemm_bt_64(const u16* __restrict__ A, const u16* __restrict__ Bt,
                const float* __restrict__ bias, OutT* __restrict__ C,
                int M, int N, int K)
{
  __shared__ u16 As[64 * 64];    //  8 KB
  __shared__ u16 Bs[128 * 64];   // 16 KB

  const int tid  = threadIdx.x;
  const int wave = tid >> 6;
  const int lane = tid & 63;
  const int lr = lane & 15;
  const int lq = lane >> 4;
  const int x7 = lr & 7;

  const int m0 = blockIdx.y * 64;
  const int n0 = blockIdx.x * 128;

  const int srow = tid >> 3;
  const int sgc  = (tid & 7) ^ (srow & 7);
  const u16* gA = A  + (size_t)(m0 + srow) * K + sgc * 8;
  const u16* gB = Bt + (size_t)(n0 + srow) * K + sgc * 8;
  u16* dstA = As + wave * 512;
  u16* dstB = Bs + wave * 512;

  f32x4 acc[4][2];
  #pragma unroll
  for (int i = 0; i < 4; ++i)
    #pragma unroll
    for (int j = 0; j < 2; ++j)
      acc[i][j] = (f32x4){0.f, 0.f, 0.f, 0.f};

  for (int k0 = 0; k0 < K; k0 += 64) {
    #pragma unroll
    for (int s = 0; s < 2; ++s)
      g2l16(gA + (size_t)(s * 32) * K + k0, dstA + s * 2048);
    #pragma unroll
    for (int s = 0; s < 4; ++s)
      g2l16(gB + (size_t)(s * 32) * K + k0, dstB + s * 2048);
    __syncthreads();

    #pragma unroll
    for (int ks = 0; ks < 2; ++ks) {
      const int pa = (ks * 4 + lq) ^ x7;
      bf16x8 af[4], bfr[2];
      #pragma unroll
      for (int im = 0; im < 4; ++im)
        af[im] = *(const bf16x8*)&As[(im * 16 + lr) * 64 + pa * 8];
      #pragma unroll
      for (int in = 0; in < 2; ++in)
        bfr[in] = *(const bf16x8*)&Bs[(wave * 32 + in * 16 + lr) * 64 + pa * 8];

      #pragma unroll
      for (int im = 0; im < 4; ++im)
        #pragma unroll
        for (int in = 0; in < 2; ++in)
          acc[im][in] = __builtin_amdgcn_mfma_f32_16x16x32_bf16(
              af[im], bfr[in], acc[im][in], 0, 0, 0);
    }
    __syncthreads();
  }

  #pragma unroll
  for (int im = 0; im < 4; ++im) {
    const int mbase = m0 + im * 16 + lq * 4;
    #pragma unroll
    for (int in = 0; in < 2; ++in) {
      const int ncol = n0 + wave * 32 + in * 16 + lr;
      #pragma unroll
      for (int r = 0; r < 4; ++r) {
        const int m = mbase + r;
        store_out(C + (size_t)m * N + ncol, acc[im][in][r] + bias[m]);
      }
    }
  }
}

// fp32 [R x C] -> bf16 [C x R], two sources selected by blockIdx.z
__global__ __launch_bounds__(256)
void cast_transpose2(const float* __restrict__ in0, u16* __restrict__ out0,
                     const float* __restrict__ in1, u16* __restrict__ out1,
                     int R, int C)
{
  const float* in = blockIdx.z ? in1 : in0;
  u16* out = blockIdx.z ? out1 : out0;
  __shared__ u16 tile[32][33];
  const int c0 = blockIdx.x * 32, r0 = blockIdx.y * 32;
  const int tx = threadIdx.x & 31, ty = threadIdx.x >> 5;
  #pragma unroll
  for (int k = 0; k < 4; ++k)
    tile[ty + 8 * k][tx] = f2b(in[(size_t)(r0 + ty + 8 * k) * C + c0 + tx]);
  __syncthreads();
  #pragma unroll
  for (int k = 0; k < 4; ++k)
    out[(size_t)(c0 + ty + 8 * k) * R + r0 + tx] = tile[tx][ty + 8 * k];
}

// bf16 [R x C] -> bf16 [C x R]
__global__ __launch_bounds__(256)
void transpose_u16(const u16* __restrict__ in, u16* __restrict__ out,
                   int R, int C)
{
  __shared__ u16 tile[32][33];
  const int c0 = blockIdx.x * 32, r0 = blockIdx.y * 32;
  const int tx = threadIdx.x & 31, ty = threadIdx.x >> 5;
  #pragma unroll
  for (int k = 0; k < 4; ++k)
    tile[ty + 8 * k][tx] = in[(size_t)(r0 + ty + 8 * k) * C + c0 + tx];
  __syncthreads();
  #pragma unroll
  for (int k = 0; k < 4; ++k)
    out[(size_t)(c0 + ty + 8 * k) * R + r0 + tx] = tile[tx][ty + 8 * k];
}

// all three weight casts in one dispatch: [Wim 1M][WL 256K][Wf 256K] float4s
__global__ __launch_bounds__(256)
void cast_weights(const float4* __restrict__ wim, const float4* __restrict__ wl,
                  const float4* __restrict__ wf, ushort4* __restrict__ wimb,
                  ushort4* __restrict__ wlb, ushort4* __restrict__ wfb)
{
  int i = blockIdx.x * 256 + threadIdx.x;
  const float4* src; ushort4* dst;
  if (i < 1048576)      { src = wim; dst = wimb; }
  else if (i < 1310720) { src = wl;  dst = wlb;  i -= 1048576; }
  else                  { src = wf;  dst = wfb;  i -= 1310720; }
  const float4 v = src[i];
  ushort4 o;
  o.x = f2b(v.x); o.y = f2b(v.y); o.z = f2b(v.z); o.w = f2b(v.w);
  dst[i] = o;
}

// spart[cb][h][n] = sum_{c in chunk cb} Q[c][n] * keys[h*1024+c][n]
__global__ __launch_bounds__(256)
void score_partial(const u16* __restrict__ keys, const float* __restrict__ Q,
                   float* __restrict__ spart)
{
  const int n  = blockIdx.x * 256 + threadIdx.x;
  const int cb = blockIdx.y;
  const int c0 = cb * 128;
  float s[4] = {0.f, 0.f, 0.f, 0.f};
  for (int c = c0; c < c0 + 128; ++c) {
    const float q = Q[(size_t)c * 4096 + n];
    #pragma unroll
    for (int h = 0; h < 4; ++h)
      s[h] = fmaf(q, b2f(keys[((size_t)((h << 10) + c)) * 4096 + n]), s[h]);
  }
  #pragma unroll
  for (int h = 0; h < 4; ++h)
    spart[((size_t)cb * 4 + h) * 4096 + n] = s[h];
}

// reduce partials, scale 1/32, softmax over 4 heads -> weightmap
__global__ __launch_bounds__(256)
void softmax_h(const float* __restrict__ spart, float* __restrict__ wmap)
{
  const int n = blockIdx.x * 256 + threadIdx.x;
  float s[4] = {0.f, 0.f, 0.f, 0.f};
  #pragma unroll
  for (int cb = 0; cb < 8; ++cb)
    #pragma unroll
    for (int h = 0; h < 4; ++h)
      s[h] += spart[((size_t)cb * 4 + h) * 4096 + n];
  #pragma unroll
  for (int h = 0; h < 4; ++h) s[h] *= 0.03125f;
  const float m = fmaxf(fmaxf(s[0], s[1]), fmaxf(s[2], s[3]));
  const float e0 = expf(s[0] - m), e1 = expf(s[1] - m);
  const float e2 = expf(s[2] - m), e3 = expf(s[3] - m);
  const float inv = 1.f / (e0 + e1 + e2 + e3);
  wmap[n] = e0 * inv; wmap[4096 + n] = e1 * inv;
  wmap[8192 + n] = e2 * inv; wmap[12288 + n] = e3 * inv;
}

// z = sum_h w[h][n]*keys[h][c][n]; t = z + Q; LayerNorm over n; bf16 out
__global__ __launch_bounds__(256)
void z_ln(const u16* __restrict__ keys, const float* __restrict__ Q,
          const float* __restrict__ w, const float* __restrict__ g,
          const float* __restrict__ bb, u16* __restrict__ fused)
{
  const int c  = blockIdx.x;
  const int tx = threadIdx.x;
  float t[16];
  float s = 0.f, s2 = 0.f;
  #pragma unroll
  for (int j = 0; j < 16; ++j) {
    const int n = tx + j * 256;
    const float q = Q[(size_t)c * 4096 + n];
    float z = 0.f;
    #pragma unroll
    for (int h = 0; h < 4; ++h)
      z = fmaf(w[h * 4096 + n], b2f(keys[((size_t)((h << 10) + c)) * 4096 + n]), z);
    const float v = z + q;
    t[j] = v; s += v; s2 = fmaf(v, v, s2);
  }
  #pragma unroll
  for (int o = 32; o > 0; o >>= 1) {
    s  += __shfl_down(s, o);
    s2 += __shfl_down(s2, o);
  }
  __shared__ float rbuf[8];
  const int wave = tx >> 6, lane = tx & 63;
  if (lane == 0) { rbuf[wave] = s; rbuf[4 + wave] = s2; }
  __syncthreads();
  s  = rbuf[0] + rbuf[1] + rbuf[2] + rbuf[3];
  s2 = rbuf[4] + rbuf[5] + rbuf[6] + rbuf[7];
  const float mu  = s * (1.f / 4096.f);
  const float var = s2 * (1.f / 4096.f) - mu * mu;
  const float rs  = rsqrtf(var + 1e-5f);
  #pragma unroll
  for (int j = 0; j < 16; ++j) {
    const int n = tx + j * 256;
    fused[(size_t)c * 4096 + n] = f2b((t[j] - mu) * rs * g[n] + bb[n]);
  }
}

extern "C" void kernel_launch(void* const* d_in, const int* in_sizes, int n_in,
                              void* d_out, int out_size, void* d_ws, size_t ws_size,
                              hipStream_t stream)
{
  const float* P   = (const float*)d_in[0];  // [1,1024,4096]
  const float* I   = (const float*)d_in[1];  // [1,1024,4096]
  const float* Wim = (const float*)d_in[2];  // [4,1024,1024]
  const float* bim = (const float*)d_in[3];  // [4,1024]
  const float* WL  = (const float*)d_in[4];  // [1024,1024]
  const float* bL  = (const float*)d_in[5];  // [1024]
  const float* lng = (const float*)d_in[6];  // [4096]
  const float* lnb = (const float*)d_in[7];  // [4096]
  const float* Wf  = (const float*)d_in[8];  // [1024,1024]
  const float* bf_ = (const float*)d_in[9];  // [1024]
  float* out = (float*)d_out;                // [1024*4096] fusion + [4*4096] wmap

  char* ws = (char*)d_ws;
  u16*   PT     = (u16*)(ws + 0);                    //  8 MB  [4096 x 1024] bf16
  u16*   IT     = (u16*)(ws + (size_t)8  * 1048576); //  8 MB
  u16*   WLb    = (u16*)(ws + (size_t)16 * 1048576); //  2 MB
  u16*   WIb    = (u16*)(ws + (size_t)18 * 1048576); //  8 MB
  u16*   WFb    = (u16*)(ws + (size_t)26 * 1048576); //  2 MB
  float* Q      = (float*)(ws + (size_t)28 * 1048576); // 16 MB [1024 x 4096]
  u16*   KEYS   = (u16*)(ws + (size_t)44 * 1048576); // 32 MB [4096 x 4096] bf16
  float* SPART  = (float*)(ws + (size_t)76 * 1048576); // 512 KB [8 x 4 x 4096]
  u16*   FUSED  = (u16*)(ws + (size_t)77 * 1048576); //  8 MB [1024 x 4096] bf16
  u16*   FUSEDT = (u16*)(ws + (size_t)85 * 1048576); //  8 MB [4096 x 1024] bf16

  const dim3 b256(256);

  // bf16 casts / transposes (P and I in one dispatch; 3 weight casts in one)
  cast_transpose2<<<dim3(128, 32, 2), b256, 0, stream>>>(P, PT, I, IT, 1024, 4096);
  cast_weights<<<6144, b256, 0, stream>>>((const float4*)Wim, (const float4*)WL,
                                          (const float4*)Wf, (ushort4*)WIb,
                                          (ushort4*)WLb, (ushort4*)WFb);

  // Q = W_L * P + b_L   [1024 x 4096] fp32  (64x128 tiles -> 512 blocks)
  gemm_bt_64<float><<<dim3(32, 16), b256, 0, stream>>>(WLb, PT, bL, Q, 1024, 4096, 1024);
  // keys = W_img * I + b_img  [4096 x 4096] bf16 (128x128 tiles -> 1024 blocks)
  gemm_bt<u16><<<dim3(32, 32), b256, 0, stream>>>(WIb, IT, bim, KEYS, 4096, 4096, 1024);

  // score partials -> softmax -> weightmap (written straight into d_out tail)
  score_partial<<<dim3(16, 8), b256, 0, stream>>>(KEYS, Q, SPART);
  float* wmap = out + (size_t)1024 * 4096;
  softmax_h<<<16, b256, 0, stream>>>(SPART, wmap);

  // z + residual + LayerNorm -> bf16, then transpose for final GEMM
  z_ln<<<1024, b256, 0, stream>>>(KEYS, Q, wmap, lng, lnb, FUSED);
  transpose_u16<<<dim3(128, 32), b256, 0, stream>>>(FUSED, FUSEDT, 1024, 4096);

  // out = W_f * fused + b_f  [1024 x 4096] fp32 -> d_out head
  gemm_bt_64<float><<<dim3(32, 16), b256, 0, stream>>>(WFb, FUSEDT, bf_, out, 1024, 4096, 1024);
}